// Round 5
// baseline (675.489 us; speedup 1.0000x reference)
//
#include <hip/hip_runtime.h>

// Fused rel-pos attention, wave-private, max-occupancy version.
// B=4, H=8, S=512, D=64, fp32 in/out.
// Block = (b, 2-row s-tile), 512 threads (8 waves). Grid = 4*256 = 1024
// -> 4 blocks/CU x 8 waves = 32 waves/CU (8/SIMD, HW max). VGPR must be
// <= 64: __launch_bounds__(512, 8) + 2-head-per-wave register tiles.
// Wave w owns (si = w>>2, head pair hp = w&3 -> heads 2hp,2hp+1) through
// ALL phases -> Pb slices wave-private -> single __syncthreads total.
// LDS: Qs fp32 [2][8][64] (4 KB) + Pb bf16 [2][512][12] (24 KB) = 28 KB.

__device__ __forceinline__ unsigned short f2bf(float x) {
  unsigned int u = __float_as_uint(x);
  u += 0x7fffu + ((u >> 16) & 1u);   // RNE
  return (unsigned short)(u >> 16);
}
__device__ __forceinline__ float bf2f(unsigned int s) {
  return __uint_as_float(s << 16);
}

__global__ __launch_bounds__(512, 8)
void attn_v5(const float* __restrict__ Q, const float* __restrict__ K,
             const float* __restrict__ V, const float* __restrict__ R,
             const int* __restrict__ Mk, float* __restrict__ ans,
             float* __restrict__ pout) {
  __shared__ __align__(16) float Qs[2][8][64];
  __shared__ __align__(16) unsigned short Pb[2][512][12];

  const int tid = threadIdx.x;
  const int b  = blockIdx.x >> 8;
  const int s0 = (blockIdx.x & 255) << 1;

  // ---------------- stage Q tile (256 float4 items, first 4 waves) ------
  if (tid < 256) {
    const int qd4 = tid & 15;
    const int qh  = (tid >> 4) & 7;
    const int qsi = tid >> 7;            // 0..1
    *reinterpret_cast<float4*>(&Qs[qsi][qh][qd4 << 2]) =
        *reinterpret_cast<const float4*>(
            Q + ((size_t)((((b << 3) + qh) << 9) + s0 + qsi) << 6) + (qd4 << 2));
  }
  __syncthreads();

  const int lane = tid & 63;
  const int w    = tid >> 6;   // 0..7
  const int si   = w >> 2;     // s-row within tile
  const int hp   = w & 3;      // head pair: heads 2hp, 2hp+1

  const float* Rb = R + (((size_t)((b << 9) + s0 + si)) << 15);
  const float* Kb = K + ((size_t)b << 18) + ((size_t)(hp << 1) << 15);

  // ---------------- Phase B: scores -> Pb (bf16, scaled, unmasked) ------
  {
    const int dgrp = lane & 15;   // d-slice of 4: d0 = dgrp*4
    const int tl   = lane >> 4;   // 0..3: t row within 4-chunk
    const int d0   = dgrp << 2;
    const bool c0  = (dgrp & 1) != 0;

    float q[2][4];
#pragma unroll
    for (int j = 0; j < 2; ++j) {
      const float4 a = *reinterpret_cast<const float4*>(&Qs[si][(hp << 1) + j][d0]);
      q[j][0] = a.x; q[j][1] = a.y; q[j][2] = a.z; q[j][3] = a.w;
    }

    auto loadKR = [&](int tt, float (&kv)[2][4], float (&rv)[4]) {
      const float4 r4 = *reinterpret_cast<const float4*>(Rb + (tt << 6) + d0);
      rv[0] = r4.x; rv[1] = r4.y; rv[2] = r4.z; rv[3] = r4.w;
#pragma unroll
      for (int j = 0; j < 2; ++j) {
        const float4 k4 = *reinterpret_cast<const float4*>(
            Kb + ((size_t)j << 15) + (tt << 6) + d0);
        kv[j][0] = k4.x; kv[j][1] = k4.y; kv[j][2] = k4.z; kv[j][3] = k4.w;
      }
    };

    auto computeB = [&](int tt, const float (&kv)[2][4], const float (&rv)[4]) {
      float s[2];
#pragma unroll
      for (int j = 0; j < 2; ++j) {
        float a = 0.0f;
#pragma unroll
        for (int d = 0; d < 4; ++d) a += q[j][d] * (kv[j][d] + rv[d]);
        s[j] = a;
      }
      // distributing stage over dgrp bit0, then plain reduce bits 1..3:
      // lane ends with full d-sum for head j = dgrp&1.
      float f = (c0 ? s[1] : s[0]) + __shfl_xor(c0 ? s[0] : s[1], 1);
      f += __shfl_xor(f, 2);
      f += __shfl_xor(f, 4);
      f += __shfl_xor(f, 8);
      if (dgrp < 2)
        Pb[si][tt][(hp << 1) + dgrp] = f2bf(f * 0.125f);
    };

    float kA[2][4], rA[4], kB[2][4], rB[4];
    loadKR(tl, kA, rA);
    for (int tc = 0; tc < 128; tc += 2) {
      const int t0 = (tc << 2) + tl;
      loadKR(t0 + 4, kB, rB);
      computeB(t0, kA, rA);
      if (tc < 126) loadKR(t0 + 8, kA, rA);
      computeB(t0 + 4, kB, rB);
    }
  }

  // ------- Phase C: softmax rows (wave-private, NO barrier needed) ------
  {
    float bias[8];
#pragma unroll
    for (int k = 0; k < 8; ++k)
      bias[k] = Mk[(b << 9) + lane + (k << 6)] ? 0.0f : -1.0e9f;

#pragma unroll
    for (int rr = 0; rr < 2; ++rr) {
      const int h = (hp << 1) + rr;
      float v[8];
#pragma unroll
      for (int k = 0; k < 8; ++k)
        v[k] = bf2f((unsigned int)Pb[si][lane + (k << 6)][h]) + bias[k];

      float m = v[0];
#pragma unroll
      for (int k = 1; k < 8; ++k) m = fmaxf(m, v[k]);
      m = fmaxf(m, __shfl_xor(m, 1));
      m = fmaxf(m, __shfl_xor(m, 2));
      m = fmaxf(m, __shfl_xor(m, 4));
      m = fmaxf(m, __shfl_xor(m, 8));
      m = fmaxf(m, __shfl_xor(m, 16));
      m = fmaxf(m, __shfl_xor(m, 32));

      float e[8], ss = 0.0f;
#pragma unroll
      for (int k = 0; k < 8; ++k) { e[k] = __expf(v[k] - m); ss += e[k]; }
      ss += __shfl_xor(ss, 1);
      ss += __shfl_xor(ss, 2);
      ss += __shfl_xor(ss, 4);
      ss += __shfl_xor(ss, 8);
      ss += __shfl_xor(ss, 16);
      ss += __shfl_xor(ss, 32);
      const float inv = 1.0f / ss;

      float* po = pout + ((size_t)((((b << 3) + h) << 9) + s0 + si) << 9);
#pragma unroll
      for (int k = 0; k < 8; ++k) {
        const float p = e[k] * inv;
        po[lane + (k << 6)] = p;
        Pb[si][lane + (k << 6)][h] = f2bf(p);
      }
    }
  }

  // ------- Phase D: out = P @ (V + R) (wave-private, NO barrier) --------
  {
    const int d4 = lane & 15, tg = lane >> 4;
    const int dd = d4 << 2;
    const float* Vb = V + ((size_t)b << 18) + ((size_t)(hp << 1) << 15);

    float acc[2][4];
#pragma unroll
    for (int j = 0; j < 2; ++j)
#pragma unroll
      for (int c = 0; c < 4; ++c) acc[j][c] = 0.0f;

    auto loadD = [&](int tt, float4 (&v4)[2], float4& r4) {
      r4 = *reinterpret_cast<const float4*>(Rb + (tt << 6) + dd);
#pragma unroll
      for (int j = 0; j < 2; ++j)
        v4[j] = *reinterpret_cast<const float4*>(
            Vb + ((size_t)j << 15) + (tt << 6) + dd);
    };

    auto computeD = [&](int tt, const float4 (&v4)[2], const float4& r4) {
      const unsigned int pw =
          *reinterpret_cast<const unsigned int*>(&Pb[si][tt][hp << 1]);
      float p[2];
      p[0] = bf2f(pw & 0xffffu);
      p[1] = bf2f(pw >> 16);
#pragma unroll
      for (int j = 0; j < 2; ++j) {
        acc[j][0] += p[j] * (v4[j].x + r4.x);
        acc[j][1] += p[j] * (v4[j].y + r4.y);
        acc[j][2] += p[j] * (v4[j].z + r4.z);
        acc[j][3] += p[j] * (v4[j].w + r4.w);
      }
    };

    float4 vA[2], rA4, vB[2], rB4;
    loadD(tg, vA, rA4);
    for (int i = 0; i < 128; i += 2) {
      const int t0 = (i << 2) + tg;
      loadD(t0 + 4, vB, rB4);
      computeD(t0, vA, rA4);
      if (i < 126) loadD(t0 + 8, vA, rA4);
      computeD(t0 + 4, vB, rB4);
    }

    // reduce across the 4 tg groups (lane bits 4,5)
#pragma unroll
    for (int j = 0; j < 2; ++j)
#pragma unroll
      for (int c = 0; c < 4; ++c) {
        float x = acc[j][c];
        x += __shfl_xor(x, 16);
        x += __shfl_xor(x, 32);
        acc[j][c] = x;
      }

    if (tg == 0) {
#pragma unroll
      for (int j = 0; j < 2; ++j) {
        float4 o;
        o.x = acc[j][0]; o.y = acc[j][1]; o.z = acc[j][2]; o.w = acc[j][3];
        *reinterpret_cast<float4*>(
            ans + ((size_t)((((b << 3) + (hp << 1) + j) << 9) + s0 + si) << 6) + dd) = o;
      }
    }
  }
}

extern "C" void kernel_launch(void* const* d_in, const int* in_sizes, int n_in,
                              void* d_out, int out_size, void* d_ws, size_t ws_size,
                              hipStream_t stream) {
  const float* Q  = (const float*)d_in[0];
  const float* K  = (const float*)d_in[1];
  const float* V  = (const float*)d_in[2];
  const float* R  = (const float*)d_in[3];
  const int*   Mk = (const int*)d_in[4];
  float* ans  = (float*)d_out;
  float* pout = ans + (size_t)4 * 8 * 512 * 64;  // p_attn after ans

  hipLaunchKernelGGL(attn_v5, dim3(1024), dim3(512), 0, stream,
                     Q, K, V, R, Mk, ans, pout);
}

// Round 6
// 206.328 us; speedup vs baseline: 3.2739x; 3.2739x over previous
//
#include <hip/hip_runtime.h>

// Rel-pos attention, MFMA restructure. B=4, H=8, S=512, D=64, fp32 in/out.
//
// K1 (qk_mfma): SK[b,h,s,t] = Q.K^T (unscaled fp32) -> pout (scratch use of
//   the p_attn output buffer; K2 overwrites it with final p every call).
// K2 (attn_v6): per (b, 2-row s-tile):
//   B': S^T[t,h] = R[si].Q[si]^T via mfma_16x16x32_bf16, C-init from SK,
//       R streamed global->reg->MFMA (each element read once per block).
//   C : wave-parallel softmax (scale 1/8 + mask folded at read), write p.
//   D : out = P.(V+R) in VALU with 3-deep register prefetch.

typedef __attribute__((ext_vector_type(8))) short short8;
typedef __attribute__((ext_vector_type(4))) float f32x4;

#define MFMA16(a, b, c) __builtin_amdgcn_mfma_f32_16x16x32_bf16(a, b, c, 0, 0, 0)

__device__ __forceinline__ unsigned short f2bf(float x) {
  unsigned int u = __float_as_uint(x);
  u += 0x7fffu + ((u >> 16) & 1u);   // RNE
  return (unsigned short)(u >> 16);
}
__device__ __forceinline__ float bf2f(unsigned int s) {
  return __uint_as_float(s << 16);
}
__device__ __forceinline__ short8 pack8(const float4& a, const float4& b) {
  short8 r;
  r[0] = (short)f2bf(a.x); r[1] = (short)f2bf(a.y);
  r[2] = (short)f2bf(a.z); r[3] = (short)f2bf(a.w);
  r[4] = (short)f2bf(b.x); r[5] = (short)f2bf(b.y);
  r[6] = (short)f2bf(b.z); r[7] = (short)f2bf(b.w);
  return r;
}

// ---------------- Kernel 1: SK = Q.K^T per (b,h), 64x64 tiles ----------------
// grid 2048: bh = bid>>6 (32), tile = bid&63 -> (s-tile, t-tile) of 8x8.
// Wave w computes the 16x64 strip s = s0+w*16.. ; A-frag row=lane&15,
// k-chunk=(lane>>4)*8 (contiguous d). D: col=lane&15 (t), row=(lane>>4)*4+reg.
__global__ __launch_bounds__(256, 4)
void qk_mfma(const float* __restrict__ Q, const float* __restrict__ K,
             float* __restrict__ skout) {
  const int bh   = blockIdx.x >> 6;
  const int tile = blockIdx.x & 63;
  const int s0 = (tile >> 3) << 6;
  const int t0 = (tile & 7) << 6;
  const int w    = threadIdx.x >> 6;
  const int lane = threadIdx.x & 63;
  const int rrow = lane & 15;
  const int kg   = lane >> 4;

  const float* Qb = Q + ((size_t)bh << 15);
  const float* Kb = K + ((size_t)bh << 15);

  const float* qp = Qb + (((s0 + (w << 4) + rrow) << 6) + (kg << 3));
  const float4 qa0 = *reinterpret_cast<const float4*>(qp);
  const float4 qa1 = *reinterpret_cast<const float4*>(qp + 4);
  const float4 qa2 = *reinterpret_cast<const float4*>(qp + 32);
  const float4 qa3 = *reinterpret_cast<const float4*>(qp + 36);
  const short8 a0 = pack8(qa0, qa1);
  const short8 a1 = pack8(qa2, qa3);

  float* outb = skout + ((size_t)bh << 18);

  float4 b0, b1, b2, b3;
  {
    const float* kp = Kb + (((t0 + rrow) << 6) + (kg << 3));
    b0 = *reinterpret_cast<const float4*>(kp);
    b1 = *reinterpret_cast<const float4*>(kp + 4);
    b2 = *reinterpret_cast<const float4*>(kp + 32);
    b3 = *reinterpret_cast<const float4*>(kp + 36);
  }
#pragma unroll
  for (int nt = 0; nt < 4; ++nt) {
    const short8 bb0 = pack8(b0, b1);
    const short8 bb1 = pack8(b2, b3);
    if (nt < 3) {  // prefetch next B tile
      const float* kp = Kb + (((t0 + ((nt + 1) << 4) + rrow) << 6) + (kg << 3));
      b0 = *reinterpret_cast<const float4*>(kp);
      b1 = *reinterpret_cast<const float4*>(kp + 4);
      b2 = *reinterpret_cast<const float4*>(kp + 32);
      b3 = *reinterpret_cast<const float4*>(kp + 36);
    }
    f32x4 c = {0.0f, 0.0f, 0.0f, 0.0f};
    c = MFMA16(a0, bb0, c);
    c = MFMA16(a1, bb1, c);
    const int tcol = t0 + (nt << 4) + rrow;
    const int srow = s0 + (w << 4) + (kg << 2);
#pragma unroll
    for (int r = 0; r < 4; ++r)
      outb[(size_t)(srow + r) * 512 + tcol] = c[r];
  }
}

// ---------------- Kernel 2: fused rel-score + softmax + output ----------------
__global__ __launch_bounds__(256, 4)
void attn_v6(const float* __restrict__ Q, const float* __restrict__ V,
             const float* __restrict__ R, const int* __restrict__ Mk,
             float* __restrict__ ans, float* __restrict__ pout) {
  __shared__ __align__(16) unsigned short Qs[2][8][72];   // bf16 Q, padded
  __shared__ __align__(16) unsigned short Pb[2][512][12]; // bf16 scores -> p

  const int tid = threadIdx.x;
  const int b  = blockIdx.x >> 8;
  const int s0 = (blockIdx.x & 255) << 1;

  // stage Q tile as bf16 (1024 elems, 4 per thread)
  {
    const int dq  = tid & 15;
    const int qh  = (tid >> 4) & 7;
    const int qsi = tid >> 7;
    const float4 qv = *reinterpret_cast<const float4*>(
        Q + ((size_t)((((b << 3) + qh) << 9) + s0 + qsi) << 6) + (dq << 2));
    unsigned short* dst = &Qs[qsi][qh][dq << 2];
    dst[0] = f2bf(qv.x); dst[1] = f2bf(qv.y);
    dst[2] = f2bf(qv.z); dst[3] = f2bf(qv.w);
  }
  __syncthreads();

  const int lane = tid & 63;
  const int w    = tid >> 6;
  const int si   = w >> 1;
  const int hg   = w & 1;

  const float* Rb = R + (((size_t)((b << 9) + s0 + si)) << 15);

  // -------- Phase B': S^T[t,h] = R.Q^T + SK, MFMA, per si --------
  {
    const int rrow = lane & 15;
    const int kg   = lane >> 4;
    const int hq   = rrow & 7;
    const bool hvalid = rrow < 8;

    const short8 bq0 = *reinterpret_cast<const short8*>(&Qs[si][hq][kg << 3]);
    const short8 bq1 = *reinterpret_cast<const short8*>(&Qs[si][hq][32 + (kg << 3)]);

    const float* pko = pout + ((size_t)((((b << 3) + hq) << 9) + s0 + si) << 9);

    auto loadA = [&](int t0, float4& a0, float4& a1, float4& a2, float4& a3,
                     float4& ci) {
      const float* rp = Rb + ((t0 + rrow) << 6) + (kg << 3);
      a0 = *reinterpret_cast<const float4*>(rp);
      a1 = *reinterpret_cast<const float4*>(rp + 4);
      a2 = *reinterpret_cast<const float4*>(rp + 32);
      a3 = *reinterpret_cast<const float4*>(rp + 36);
      ci = hvalid ? *reinterpret_cast<const float4*>(pko + t0 + (kg << 2))
                  : make_float4(0.0f, 0.0f, 0.0f, 0.0f);
    };
    auto compB = [&](int t0, const float4& a0, const float4& a1,
                     const float4& a2, const float4& a3, const float4& ci) {
      const short8 aa0 = pack8(a0, a1);
      const short8 aa1 = pack8(a2, a3);
      f32x4 c;
      c[0] = ci.x; c[1] = ci.y; c[2] = ci.z; c[3] = ci.w;
      c = MFMA16(aa0, bq0, c);
      c = MFMA16(aa1, bq1, c);
      if (hvalid) {
#pragma unroll
        for (int r = 0; r < 4; ++r)
          Pb[si][t0 + (kg << 2) + r][hq] = f2bf(c[r]);
      }
    };

    const int base = hg << 8;   // this wave's 256-t half
    float4 xa0, xa1, xa2, xa3, xci, ya0, ya1, ya2, ya3, yci;
    loadA(base, xa0, xa1, xa2, xa3, xci);
    for (int j = 0; j < 16; j += 2) {
      const int ta = base + (j << 4);
      loadA(ta + 16, ya0, ya1, ya2, ya3, yci);
      compB(ta, xa0, xa1, xa2, xa3, xci);
      if (j < 14) loadA(ta + 32, xa0, xa1, xa2, xa3, xci);
      compB(ta + 16, ya0, ya1, ya2, ya3, yci);
    }
  }
  __syncthreads();

  // -------- Phase C: softmax (scale 1/8 + mask folded), write p --------
  {
    float bias[8];
#pragma unroll
    for (int k = 0; k < 8; ++k)
      bias[k] = Mk[(b << 9) + lane + (k << 6)] ? 0.0f : -1.0e9f;

#pragma unroll
    for (int rr = 0; rr < 4; ++rr) {
      const int h = (hg << 2) + rr;
      float v[8];
#pragma unroll
      for (int k = 0; k < 8; ++k)
        v[k] = bf2f((unsigned int)Pb[si][lane + (k << 6)][h]) * 0.125f + bias[k];

      float m = v[0];
#pragma unroll
      for (int k = 1; k < 8; ++k) m = fmaxf(m, v[k]);
      m = fmaxf(m, __shfl_xor(m, 1));
      m = fmaxf(m, __shfl_xor(m, 2));
      m = fmaxf(m, __shfl_xor(m, 4));
      m = fmaxf(m, __shfl_xor(m, 8));
      m = fmaxf(m, __shfl_xor(m, 16));
      m = fmaxf(m, __shfl_xor(m, 32));

      float e[8], ss = 0.0f;
#pragma unroll
      for (int k = 0; k < 8; ++k) { e[k] = __expf(v[k] - m); ss += e[k]; }
      ss += __shfl_xor(ss, 1);
      ss += __shfl_xor(ss, 2);
      ss += __shfl_xor(ss, 4);
      ss += __shfl_xor(ss, 8);
      ss += __shfl_xor(ss, 16);
      ss += __shfl_xor(ss, 32);
      const float inv = 1.0f / ss;

      float* po = pout + ((size_t)((((b << 3) + h) << 9) + s0 + si) << 9);
#pragma unroll
      for (int k = 0; k < 8; ++k) {
        const float p = e[k] * inv;
        po[lane + (k << 6)] = p;
        Pb[si][lane + (k << 6)][h] = f2bf(p);
      }
    }
  }
  // no barrier: phase D reads only this wave's (si, hg) rows of Pb

  // -------- Phase D: out = P.(V+R), VALU, 3-deep prefetch --------
  {
    const int d4 = lane & 15, tg = lane >> 4;
    const int dd = d4 << 2;
    const float* Vb = V + ((size_t)b << 18) + (((size_t)(hg << 2)) << 15);

    float acc[4][4];
#pragma unroll
    for (int hh = 0; hh < 4; ++hh)
#pragma unroll
      for (int c = 0; c < 4; ++c) acc[hh][c] = 0.0f;

    auto loadD = [&](int tt, float4* v4, float4& r4) {
      r4 = *reinterpret_cast<const float4*>(Rb + (tt << 6) + dd);
#pragma unroll
      for (int j = 0; j < 4; ++j)
        v4[j] = *reinterpret_cast<const float4*>(
            Vb + ((size_t)j << 15) + (tt << 6) + dd);
    };
    auto compD = [&](int tt, const float4* v4, const float4& r4) {
      const unsigned int* pw =
          reinterpret_cast<const unsigned int*>(&Pb[si][tt][hg << 2]);
      const unsigned int p01 = pw[0], p23 = pw[1];
      float p[4];
      p[0] = bf2f(p01 & 0xffffu); p[1] = bf2f(p01 >> 16);
      p[2] = bf2f(p23 & 0xffffu); p[3] = bf2f(p23 >> 16);
#pragma unroll
      for (int hh = 0; hh < 4; ++hh) {
        acc[hh][0] += p[hh] * (v4[hh].x + r4.x);
        acc[hh][1] += p[hh] * (v4[hh].y + r4.y);
        acc[hh][2] += p[hh] * (v4[hh].z + r4.z);
        acc[hh][3] += p[hh] * (v4[hh].w + r4.w);
      }
    };

    float4 vA[4], vB[4], vC[4], rA, rB, rC;
    loadD(tg, vA, rA);
    loadD(4 + tg, vB, rB);
    loadD(8 + tg, vC, rC);
    for (int i = 0; i < 126; i += 3) {
      compD((i << 2) + tg, vA, rA);
      loadD(((i + 3) << 2) + tg, vA, rA);
      compD(((i + 1) << 2) + tg, vB, rB);
      { int tn = ((i + 4) << 2) + tg; if (tn > 511) tn -= 512; loadD(tn, vB, rB); }
      compD(((i + 2) << 2) + tg, vC, rC);
      { int tn = ((i + 5) << 2) + tg; if (tn > 511) tn -= 512; loadD(tn, vC, rC); }
    }
    compD(504 + tg, vA, rA);
    compD(508 + tg, vB, rB);

#pragma unroll
    for (int hh = 0; hh < 4; ++hh)
#pragma unroll
      for (int c = 0; c < 4; ++c) {
        float x = acc[hh][c];
        x += __shfl_xor(x, 16);
        x += __shfl_xor(x, 32);
        acc[hh][c] = x;
      }

    if (tg == 0) {
#pragma unroll
      for (int hh = 0; hh < 4; ++hh) {
        float4 o;
        o.x = acc[hh][0]; o.y = acc[hh][1];
        o.z = acc[hh][2]; o.w = acc[hh][3];
        *reinterpret_cast<float4*>(
            ans + ((size_t)((((b << 3) + (hg << 2) + hh) << 9) + s0 + si) << 6) + dd) = o;
      }
    }
  }
}

extern "C" void kernel_launch(void* const* d_in, const int* in_sizes, int n_in,
                              void* d_out, int out_size, void* d_ws, size_t ws_size,
                              hipStream_t stream) {
  const float* Q  = (const float*)d_in[0];
  const float* K  = (const float*)d_in[1];
  const float* V  = (const float*)d_in[2];
  const float* R  = (const float*)d_in[3];
  const int*   Mk = (const int*)d_in[4];
  float* ans  = (float*)d_out;
  float* pout = ans + (size_t)4 * 8 * 512 * 64;  // p_attn region (also SK scratch)
  (void)d_ws; (void)ws_size; (void)in_sizes; (void)n_in; (void)out_size;

  hipLaunchKernelGGL(qk_mfma, dim3(2048), dim3(256), 0, stream, Q, K, pout);
  hipLaunchKernelGGL(attn_v6, dim3(1024), dim3(256), 0, stream,
                     Q, V, R, Mk, ans, pout);
}

// Round 7
// 113.745 us; speedup vs baseline: 5.9386x; 1.8140x over previous
//
#include <hip/hip_runtime.h>

// Rel-pos attention, fully re-tiled MFMA design. B=4, H=8, S=512, D=64.
//
// K1 qk_mfma : SK[b,h,s,t] = Q.K^T (fp32) -> pout scratch (overwritten by K2).
// K2 attn_v7 : one block per (b,s). Stage R[b,s] (512x64) -> LDS bf16 ONCE.
//              rel = Q.R^T (MFMA) -> Sb; softmax(rel+SK, mask) -> p (global+Sb);
//              ans2 = P.R (MFMA) -> ans.   R read exactly once from HBM.
// K3 pv_mfma : one block per (b,h,s-tile64). Stage V[b,h] -> LDS bf16;
//              ans += P.V (MFMA), P streamed fp32 from pout.
//
// LDS swizzle slot(t) = (t&7)^((t>>3)&7), XORed into bits 3..5 of the u16
// index: rel B-frags (16 rows, same col-range) -> 2-way; ans2/K3 B-frags
// (rows j+{0,8,16,24}) -> conflict-free; staging writes unaffected.

typedef __attribute__((ext_vector_type(8))) short short8;
typedef __attribute__((ext_vector_type(4))) float f32x4;

#define MFMA16(a, b, c) __builtin_amdgcn_mfma_f32_16x16x32_bf16(a, b, c, 0, 0, 0)

__device__ __forceinline__ unsigned short f2bf(float x) {
  unsigned int u = __float_as_uint(x);
  u += 0x7fffu + ((u >> 16) & 1u);   // RNE
  return (unsigned short)(u >> 16);
}
__device__ __forceinline__ float bf2f(unsigned int s) {
  return __uint_as_float(s << 16);
}
__device__ __forceinline__ short8 pack8(const float4& a, const float4& b) {
  short8 r;
  r[0] = (short)f2bf(a.x); r[1] = (short)f2bf(a.y);
  r[2] = (short)f2bf(a.z); r[3] = (short)f2bf(a.w);
  r[4] = (short)f2bf(b.x); r[5] = (short)f2bf(b.y);
  r[6] = (short)f2bf(b.z); r[7] = (short)f2bf(b.w);
  return r;
}
// u16-unit LDS indices
__device__ __forceinline__ int RLI(int t, int d) {
  return ((t << 6) | d) ^ ((((t & 7) ^ ((t >> 3) & 7))) << 3);
}
__device__ __forceinline__ int SBI(int h, int t) {
  return ((h << 9) | t) ^ ((h & 7) << 3);
}

// ---------------- K1: SK = Q.K^T per (b,h), 64x64 tiles (proven r6) -------
__global__ __launch_bounds__(256, 4)
void qk_mfma(const float* __restrict__ Q, const float* __restrict__ K,
             float* __restrict__ skout) {
  const int bh   = blockIdx.x >> 6;
  const int tile = blockIdx.x & 63;
  const int s0 = (tile >> 3) << 6;
  const int t0 = (tile & 7) << 6;
  const int w    = threadIdx.x >> 6;
  const int lane = threadIdx.x & 63;
  const int rrow = lane & 15;
  const int kg   = lane >> 4;

  const float* Qb = Q + ((size_t)bh << 15);
  const float* Kb = K + ((size_t)bh << 15);

  const float* qp = Qb + (((s0 + (w << 4) + rrow) << 6) + (kg << 3));
  const short8 a0 = pack8(*reinterpret_cast<const float4*>(qp),
                          *reinterpret_cast<const float4*>(qp + 4));
  const short8 a1 = pack8(*reinterpret_cast<const float4*>(qp + 32),
                          *reinterpret_cast<const float4*>(qp + 36));

  float* outb = skout + ((size_t)bh << 18);

  float4 b0, b1, b2, b3;
  {
    const float* kp = Kb + (((t0 + rrow) << 6) + (kg << 3));
    b0 = *reinterpret_cast<const float4*>(kp);
    b1 = *reinterpret_cast<const float4*>(kp + 4);
    b2 = *reinterpret_cast<const float4*>(kp + 32);
    b3 = *reinterpret_cast<const float4*>(kp + 36);
  }
#pragma unroll
  for (int nt = 0; nt < 4; ++nt) {
    const short8 bb0 = pack8(b0, b1);
    const short8 bb1 = pack8(b2, b3);
    if (nt < 3) {
      const float* kp = Kb + (((t0 + ((nt + 1) << 4) + rrow) << 6) + (kg << 3));
      b0 = *reinterpret_cast<const float4*>(kp);
      b1 = *reinterpret_cast<const float4*>(kp + 4);
      b2 = *reinterpret_cast<const float4*>(kp + 32);
      b3 = *reinterpret_cast<const float4*>(kp + 36);
    }
    f32x4 c = {0.0f, 0.0f, 0.0f, 0.0f};
    c = MFMA16(a0, bb0, c);
    c = MFMA16(a1, bb1, c);
    const int tcol = t0 + (nt << 4) + rrow;
    const int srow = s0 + (w << 4) + (kg << 2);
#pragma unroll
    for (int r = 0; r < 4; ++r)
      outb[(size_t)(srow + r) * 512 + tcol] = c[r];
  }
}

// ---------------- K2: per (b,s): rel + softmax + ans2 ---------------------
__global__ __launch_bounds__(256, 2)
void attn_v7(const float* __restrict__ Q, const float* __restrict__ R,
             const int* __restrict__ Mk, float* __restrict__ ans,
             float* __restrict__ pout) {
  // one array -> guaranteed layout: Sb first (A-frag rows 8..15 read OOB
  // into Rl region: garbage feeding discarded D rows only)
  __shared__ __align__(16) unsigned short smem[8 * 512 + 512 * 64];  // 72 KB
  unsigned short* Sb = smem;
  unsigned short* Rl = smem + 8 * 512;

  const int tid = threadIdx.x;
  const int b = blockIdx.x >> 9;
  const int s = blockIdx.x & 511;
  const int bh0 = b << 3;

  const float* Rg = R + ((size_t)((b << 9) + s) << 15);

  // ---- stage R[b,s] 512x64 fp32 -> Rl bf16 (swizzled), 8-deep batches ----
  {
    const int c16 = tid & 15;   // d0 = c16*4
    const int r0  = tid >> 4;   // row within 16-row stripe
#pragma unroll
    for (int pg = 0; pg < 4; ++pg) {
      float4 tmp[8];
#pragma unroll
      for (int j = 0; j < 8; ++j) {
        const int t = (((pg << 3) + j) << 4) + r0;
        tmp[j] = *reinterpret_cast<const float4*>(Rg + (t << 6) + (c16 << 2));
      }
#pragma unroll
      for (int j = 0; j < 8; ++j) {
        const int t = (((pg << 3) + j) << 4) + r0;
        unsigned short* dst = &Rl[RLI(t, c16 << 2)];
        dst[0] = f2bf(tmp[j].x); dst[1] = f2bf(tmp[j].y);
        dst[2] = f2bf(tmp[j].z); dst[3] = f2bf(tmp[j].w);
      }
    }
  }
  __syncthreads();

  const int lane = tid & 63;
  const int w    = tid >> 6;
  const int nn   = lane & 15;
  const int kg   = lane >> 4;

  // ---- rel[h,t] = Q[h,:].R[t,:]  (A=Q 16x64 padded, B=R^T) -> Sb bf16 ----
  {
    const int hq = nn & 7;
    const float* Qg = Q + ((size_t)(((bh0 + hq) << 9) + s) << 6);
    const short8 aq0 = pack8(*reinterpret_cast<const float4*>(Qg + (kg << 3)),
                             *reinterpret_cast<const float4*>(Qg + (kg << 3) + 4));
    const short8 aq1 = pack8(*reinterpret_cast<const float4*>(Qg + 32 + (kg << 3)),
                             *reinterpret_cast<const float4*>(Qg + 36 + (kg << 3)));

#pragma unroll
    for (int i = 0; i < 8; ++i) {
      const int t0 = ((w << 3) + i) << 4;
      const short8 bb0 = *reinterpret_cast<const short8*>(&Rl[RLI(t0 + nn, kg << 3)]);
      const short8 bb1 = *reinterpret_cast<const short8*>(&Rl[RLI(t0 + nn, 32 + (kg << 3))]);
      f32x4 c = {0.0f, 0.0f, 0.0f, 0.0f};
      c = MFMA16(aq0, bb0, c);
      c = MFMA16(aq1, bb1, c);
      if (kg < 2) {
#pragma unroll
        for (int r = 0; r < 4; ++r)
          Sb[SBI((kg << 2) + r, t0 + nn)] = f2bf(c[r]);
      }
    }
  }
  __syncthreads();

  // ---- softmax rows h = 2w,2w+1: (rel + SK)/8 + mask -> p ----
  {
    float bias[8];
#pragma unroll
    for (int k = 0; k < 8; ++k)
      bias[k] = Mk[(b << 9) + lane + (k << 6)] ? 0.0f : -1.0e9f;

#pragma unroll
    for (int rr = 0; rr < 2; ++rr) {
      const int h = (w << 1) + rr;
      float* po = pout + ((size_t)(bh0 + h) << 18) + ((size_t)s << 9);

      float v[8];
#pragma unroll
      for (int k = 0; k < 8; ++k) {
        const int t = lane + (k << 6);
        v[k] = (bf2f((unsigned int)Sb[SBI(h, t)]) + po[t]) * 0.125f + bias[k];
      }
      float m = v[0];
#pragma unroll
      for (int k = 1; k < 8; ++k) m = fmaxf(m, v[k]);
      m = fmaxf(m, __shfl_xor(m, 1));
      m = fmaxf(m, __shfl_xor(m, 2));
      m = fmaxf(m, __shfl_xor(m, 4));
      m = fmaxf(m, __shfl_xor(m, 8));
      m = fmaxf(m, __shfl_xor(m, 16));
      m = fmaxf(m, __shfl_xor(m, 32));

      float e[8], ss = 0.0f;
#pragma unroll
      for (int k = 0; k < 8; ++k) { e[k] = __expf(v[k] - m); ss += e[k]; }
      ss += __shfl_xor(ss, 1);
      ss += __shfl_xor(ss, 2);
      ss += __shfl_xor(ss, 4);
      ss += __shfl_xor(ss, 8);
      ss += __shfl_xor(ss, 16);
      ss += __shfl_xor(ss, 32);
      const float inv = 1.0f / ss;

#pragma unroll
      for (int k = 0; k < 8; ++k) {
        const float p = e[k] * inv;
        const int t = lane + (k << 6);
        po[t] = p;
        Sb[SBI(h, t)] = f2bf(p);
      }
    }
  }
  __syncthreads();

  // ---- ans2[h,d] = sum_t P[h,t].R[t,d]  (A=P, B=R), wave w: d-tile w*16 --
  {
    const int n0 = w << 4;
    f32x4 acc = {0.0f, 0.0f, 0.0f, 0.0f};
#pragma unroll
    for (int ks = 0; ks < 16; ++ks) {
      const int tb = (ks << 5) + (kg << 3);
      const short8 af = *reinterpret_cast<const short8*>(&Sb[SBI(nn, tb)]);
      short8 bf;
#pragma unroll
      for (int j = 0; j < 8; ++j)
        bf[j] = (short)Rl[RLI(tb + j, n0 + nn)];
      acc = MFMA16(af, bf, acc);
    }
    if (kg < 2) {
#pragma unroll
      for (int r = 0; r < 4; ++r) {
        const int h = (kg << 2) + r;
        ans[((size_t)(((bh0 + h) << 9) + s) << 6) + n0 + nn] = acc[r];
      }
    }
  }
}

// ---------------- K3: ans += P.V per (b,h), 64-row s-tiles ----------------
__global__ __launch_bounds__(256, 2)
void pv_mfma(const float* __restrict__ V, const float* __restrict__ pout,
             float* __restrict__ ans) {
  __shared__ __align__(16) unsigned short Vl[512 * 64];   // 64 KB

  const int tid = threadIdx.x;
  const int bh = blockIdx.x >> 3;
  const int s0 = (blockIdx.x & 7) << 6;

  const float* Vg = V + ((size_t)bh << 15);
  {
    const int c16 = tid & 15;
    const int r0  = tid >> 4;
#pragma unroll
    for (int pg = 0; pg < 4; ++pg) {
      float4 tmp[8];
#pragma unroll
      for (int j = 0; j < 8; ++j) {
        const int t = (((pg << 3) + j) << 4) + r0;
        tmp[j] = *reinterpret_cast<const float4*>(Vg + (t << 6) + (c16 << 2));
      }
#pragma unroll
      for (int j = 0; j < 8; ++j) {
        const int t = (((pg << 3) + j) << 4) + r0;
        unsigned short* dst = &Vl[RLI(t, c16 << 2)];
        dst[0] = f2bf(tmp[j].x); dst[1] = f2bf(tmp[j].y);
        dst[2] = f2bf(tmp[j].z); dst[3] = f2bf(tmp[j].w);
      }
    }
  }
  __syncthreads();

  const int lane = tid & 63;
  const int w    = tid >> 6;
  const int nn   = lane & 15;
  const int kg   = lane >> 4;
  const int srow = s0 + (w << 4) + nn;     // A-frag row

  const float* Pg = pout + ((size_t)bh << 18) + ((size_t)srow << 9);

  f32x4 acc0 = {0.f, 0.f, 0.f, 0.f}, acc1 = acc0, acc2 = acc0, acc3 = acc0;

  float4 pa = *reinterpret_cast<const float4*>(Pg + (kg << 3));
  float4 pb = *reinterpret_cast<const float4*>(Pg + (kg << 3) + 4);
#pragma unroll
  for (int ks = 0; ks < 16; ++ks) {
    const short8 af = pack8(pa, pb);
    if (ks < 15) {
      pa = *reinterpret_cast<const float4*>(Pg + ((ks + 1) << 5) + (kg << 3));
      pb = *reinterpret_cast<const float4*>(Pg + ((ks + 1) << 5) + (kg << 3) + 4);
    }
    const int tb = (ks << 5) + (kg << 3);
    short8 b0, b1, b2, b3;
#pragma unroll
    for (int j = 0; j < 8; ++j) {
      b0[j] = (short)Vl[RLI(tb + j, nn)];
      b1[j] = (short)Vl[RLI(tb + j, 16 + nn)];
      b2[j] = (short)Vl[RLI(tb + j, 32 + nn)];
      b3[j] = (short)Vl[RLI(tb + j, 48 + nn)];
    }
    acc0 = MFMA16(af, b0, acc0);
    acc1 = MFMA16(af, b1, acc1);
    acc2 = MFMA16(af, b2, acc2);
    acc3 = MFMA16(af, b3, acc3);
  }

  // D row = kg*4+r -> s_out; add into ans (ans2 already there)
  {
    const int sb = s0 + (w << 4) + (kg << 2);
#pragma unroll
    for (int r = 0; r < 4; ++r) {
      float* ap = ans + ((size_t)bh << 15) + ((size_t)(sb + r) << 6) + nn;
      ap[0]  += acc0[r];
      ap[16] += acc1[r];
      ap[32] += acc2[r];
      ap[48] += acc3[r];
    }
  }
}

extern "C" void kernel_launch(void* const* d_in, const int* in_sizes, int n_in,
                              void* d_out, int out_size, void* d_ws, size_t ws_size,
                              hipStream_t stream) {
  const float* Q  = (const float*)d_in[0];
  const float* K  = (const float*)d_in[1];
  const float* V  = (const float*)d_in[2];
  const float* R  = (const float*)d_in[3];
  const int*   Mk = (const int*)d_in[4];
  float* ans  = (float*)d_out;
  float* pout = ans + (size_t)4 * 8 * 512 * 64;  // p_attn region (SK scratch first)
  (void)d_ws; (void)ws_size; (void)in_sizes; (void)n_in; (void)out_size;

  hipLaunchKernelGGL(qk_mfma, dim3(2048), dim3(256), 0, stream, Q, K, pout);
  hipLaunchKernelGGL(attn_v7, dim3(2048), dim3(256), 0, stream,
                     Q, R, Mk, ans, pout);
  hipLaunchKernelGGL(pv_mfma, dim3(256), dim3(256), 0, stream, V, pout, ans);
}